// Round 1
// baseline (578.446 us; speedup 1.0000x reference)
//
#include <hip/hip_runtime.h>
#include <hip/hip_bf16.h>
#include <stdint.h>

// Problem constants (from reference setup_inputs)
#define B_DIM 8192
#define K_DIM 4096
#define D_DIM 1024

constexpr float TINY_F = 1e-8f;
constexpr float R_K   = 1.0f / (float)K_DIM;   // row marginal 1/K
constexpr float C_B   = 1.0f / (float)B_DIM;   // col marginal 1/B
constexpr float SCALE = 1.0f / (0.01f * 0.7f); // 1/(TEMPERATURE*EPSILON)

typedef __attribute__((ext_vector_type(8))) short     short8;   // 8 bf16 (MFMA frag)
typedef __attribute__((ext_vector_type(8))) unsigned short ushort8;
typedef __attribute__((ext_vector_type(4))) unsigned short ushort4v;
typedef __attribute__((ext_vector_type(4))) float     f32x4;
typedef __attribute__((ext_vector_type(4))) float     floatv4;

__device__ __forceinline__ float bf2f(unsigned short u) {
  return __builtin_bit_cast(float, (unsigned int)u << 16);
}
__device__ __forceinline__ unsigned short f2bf(float f) {
  unsigned int x = __builtin_bit_cast(unsigned int, f);
  x += 0x7FFFu + ((x >> 16) & 1u);  // round-to-nearest-even (no NaN inputs here)
  return (unsigned short)(x >> 16);
}

// ---- block reductions (256 threads = 4 waves of 64) ----
__device__ __forceinline__ float blk_sum(float v, float* sm) {
#pragma unroll
  for (int m = 32; m > 0; m >>= 1) v += __shfl_xor(v, m);
  if ((threadIdx.x & 63) == 0) sm[threadIdx.x >> 6] = v;
  __syncthreads();
  float r = sm[0] + sm[1] + sm[2] + sm[3];
  __syncthreads();
  return r;
}
__device__ __forceinline__ float blk_max(float v, float* sm) {
#pragma unroll
  for (int m = 32; m > 0; m >>= 1) v = fmaxf(v, __shfl_xor(v, m));
  if ((threadIdx.x & 63) == 0) sm[threadIdx.x >> 6] = v;
  __syncthreads();
  float r = fmaxf(fmaxf(sm[0], sm[1]), fmaxf(sm[2], sm[3]));
  __syncthreads();
  return r;
}

// ---- f32 -> bf16 convert (features) ----
__global__ __launch_bounds__(256) void cvt_kernel(const float* __restrict__ in,
                                                  unsigned short* __restrict__ out) {
  const int i = (blockIdx.x * 256 + threadIdx.x) * 4;
  floatv4 v = *(const floatv4*)(in + i);
  ushort4v o = { f2bf(v[0]), f2bf(v[1]), f2bf(v[2]), f2bf(v[3]) };
  *(ushort4v*)(out + i) = o;
}

// ---- row-normalize prototypes -> bf16 ----
__global__ __launch_bounds__(256) void protonorm_kernel(const float* __restrict__ w,
                                                        unsigned short* __restrict__ wbf) {
  const int k = blockIdx.x;
  const floatv4* pr = (const floatv4*)(w + (size_t)k * D_DIM) + threadIdx.x;
  floatv4 v = *pr;
  float ss = v[0]*v[0] + v[1]*v[1] + v[2]*v[2] + v[3]*v[3];
  __shared__ float sm[8];
  float tot = blk_sum(ss, sm);
  float inv = 1.0f / sqrtf(tot);
  ushort4v o = { f2bf(v[0]*inv), f2bf(v[1]*inv), f2bf(v[2]*inv), f2bf(v[3]*inv) };
  *((ushort4v*)(wbf + (size_t)k * D_DIM) + threadIdx.x) = o;
}

// ---- per-row logsumexp of logits: mpl[b] = max + log(sum exp(x-max)) ----
__global__ __launch_bounds__(256) void lse_kernel(const float* __restrict__ logits,
                                                  float* __restrict__ mpl) {
  const int b = blockIdx.x;
  const floatv4* p = (const floatv4*)(logits + (size_t)b * K_DIM) + threadIdx.x * 4;
  floatv4 r0 = p[0], r1 = p[1], r2 = p[2], r3 = p[3];
  float m = r0[0];
#pragma unroll
  for (int j = 0; j < 4; ++j) {
    m = fmaxf(m, r0[j]); m = fmaxf(m, r1[j]);
    m = fmaxf(m, r2[j]); m = fmaxf(m, r3[j]);
  }
  __shared__ float sm[8];
  float M = blk_max(m, sm);
  float s = 0.f;
#pragma unroll
  for (int j = 0; j < 4; ++j) {
    s += __expf(r0[j] - M) + __expf(r1[j] - M) + __expf(r2[j] - M) + __expf(r3[j] - M);
  }
  float S = blk_sum(s, sm);
  if (threadIdx.x == 0) mpl[b] = M + __logf(S);
}

// ---- GEMM: E[b,k] = exp( (feat_b . w_k) * SCALE ), bf16 output ----
// 128x128 tile, BK=32, 4 waves (2x2), 16x16x32 bf16 MFMA, global_load_lds width16.
__device__ __forceinline__ void gload_lds16(const unsigned short* g, unsigned short* l) {
  __builtin_amdgcn_global_load_lds(
      (const __attribute__((address_space(1))) void*)g,
      (__attribute__((address_space(3))) void*)l, 16, 0, 0);
}

__global__ __launch_bounds__(256) void gemm_exp_kernel(const unsigned short* __restrict__ fbf,
                                                       const unsigned short* __restrict__ wbf,
                                                       unsigned short* __restrict__ Emat) {
  __shared__ unsigned short sA[128 * 32];
  __shared__ unsigned short sB[128 * 32];
  const int tid  = threadIdx.x;
  const int lane = tid & 63;
  const int wid  = tid >> 6;
  const int wr = wid >> 1, wc = wid & 1;
  const int m0 = blockIdx.x * 128;
  const int n0 = blockIdx.y * 128;

  f32x4 acc[4][4];
#pragma unroll
  for (int i = 0; i < 4; ++i)
#pragma unroll
    for (int j = 0; j < 4; ++j) acc[i][j] = (f32x4){0.f, 0.f, 0.f, 0.f};

  // staging: 8 chunks of 16 rows x 32 cols per matrix; wave w owns chunks 2w, 2w+1
  const int srow = (wid * 2) * 16 + (lane >> 2);
  const int scol = (lane & 3) * 8;
  const unsigned short* ga0 = fbf + (size_t)(m0 + srow) * D_DIM + scol;
  const unsigned short* gb0 = wbf + (size_t)(n0 + srow) * D_DIM + scol;
  unsigned short* la0 = &sA[(wid * 2) * 512];
  unsigned short* lb0 = &sB[(wid * 2) * 512];

  const int fr = lane & 15;
  const int fk = (lane >> 4) * 8;

  for (int kt = 0; kt < D_DIM / 32; ++kt) {
    const int kk = kt * 32;
    if (kt) __syncthreads();
    gload_lds16(ga0 + kk,              la0);
    gload_lds16(ga0 + 16 * D_DIM + kk, la0 + 512);
    gload_lds16(gb0 + kk,              lb0);
    gload_lds16(gb0 + 16 * D_DIM + kk, lb0 + 512);
    __syncthreads();  // compiler emits vmcnt(0) before barrier

    short8 af[4], bfr[4];
#pragma unroll
    for (int mi = 0; mi < 4; ++mi)
      af[mi] = *(const short8*)&sA[(wr * 64 + mi * 16 + fr) * 32 + fk];
#pragma unroll
    for (int ni = 0; ni < 4; ++ni)
      bfr[ni] = *(const short8*)&sB[(wc * 64 + ni * 16 + fr) * 32 + fk];
#pragma unroll
    for (int mi = 0; mi < 4; ++mi)
#pragma unroll
      for (int ni = 0; ni < 4; ++ni)
        acc[mi][ni] = __builtin_amdgcn_mfma_f32_16x16x32_bf16(af[mi], bfr[ni], acc[mi][ni], 0, 0, 0);
  }

  // epilogue: C/D layout col=lane&15, row=(lane>>4)*4+reg
  const int fq = lane >> 4;
#pragma unroll
  for (int mi = 0; mi < 4; ++mi) {
#pragma unroll
    for (int r = 0; r < 4; ++r) {
      const int row = m0 + wr * 64 + mi * 16 + fq * 4 + r;
      const size_t base = (size_t)row * K_DIM + n0 + wc * 64 + fr;
#pragma unroll
      for (int ni = 0; ni < 4; ++ni) {
        float z = acc[mi][ni][r] * SCALE;
        Emat[base + ni * 16] = f2bf(__expf(z));
      }
    }
  }
}

// ---- row pass: s[b] = sum_k E[b,k]*alpha[k]; INIT: beta=1/s ; else beta *= c/(beta*s+TINY) ----
template <int INIT>
__global__ __launch_bounds__(256) void row_kernel(const unsigned short* __restrict__ Emat,
                                                  const float* __restrict__ alpha,
                                                  float* __restrict__ beta) {
  const int b = blockIdx.x;
  const ushort8* pe = (const ushort8*)(Emat + (size_t)b * K_DIM) + threadIdx.x * 2;
  ushort8 e0 = pe[0], e1 = pe[1];
  float s = 0.f;
  if (INIT) {
#pragma unroll
    for (int j = 0; j < 8; ++j) s += bf2f(e0[j]) + bf2f(e1[j]);
  } else {
    const floatv4* pa = (const floatv4*)alpha + threadIdx.x * 4;
    floatv4 a0 = pa[0], a1 = pa[1], a2 = pa[2], a3 = pa[3];
#pragma unroll
    for (int j = 0; j < 4; ++j) {
      s += bf2f(e0[j])     * a0[j];
      s += bf2f(e0[4 + j]) * a1[j];
      s += bf2f(e1[j])     * a2[j];
      s += bf2f(e1[4 + j]) * a3[j];
    }
  }
  __shared__ float sm[8];
  float tot = blk_sum(s, sm);
  if (threadIdx.x == 0) {
    if (INIT) {
      beta[b] = 1.0f / tot;
    } else {
      float bb = beta[b];
      float v  = bb * tot;
      beta[b]  = bb * (C_B / (v + TINY_F));
    }
  }
}

// ---- col pass: t[k] += sum_b E[b,k]*beta[b] over a 64-row chunk ----
__global__ __launch_bounds__(256) void col_kernel(const unsigned short* __restrict__ Emat,
                                                  const float* __restrict__ beta,
                                                  float* __restrict__ tbuf) {
  const int k0 = (blockIdx.x * 256 + threadIdx.x) * 8;
  const int b0 = blockIdx.y * 64;
  const ushort8* p = (const ushort8*)(Emat + (size_t)b0 * K_DIM + k0);
  float acc[8] = {0.f, 0.f, 0.f, 0.f, 0.f, 0.f, 0.f, 0.f};
  for (int i = 0; i < 64; ++i) {
    ushort8 e = p[(size_t)i * (K_DIM / 8)];
    float bb = beta[b0 + i];
#pragma unroll
    for (int j = 0; j < 8; ++j) acc[j] = fmaf(bf2f(e[j]), bb, acc[j]);
  }
#pragma unroll
  for (int j = 0; j < 8; ++j) atomicAdd(&tbuf[k0 + j], acc[j]);
}

// ---- alpha update: u = alpha*t; alpha *= r/(u+TINY) (FIRST: alpha was 1) ----
template <int FIRST>
__global__ __launch_bounds__(256) void alpha_kernel(const float* __restrict__ tbuf,
                                                    float* __restrict__ alpha) {
  const int k = blockIdx.x * 256 + threadIdx.x;
  float t = tbuf[k];
  if (FIRST) {
    alpha[k] = R_K / (t + TINY_F);
  } else {
    float a = alpha[k];
    alpha[k] = a * R_K / (a * t + TINY_F);
  }
}

// ---- loss: contrib[b] = mpl[b] - (sum Ea*logits)/(sum Ea); out += contrib/B ----
__global__ __launch_bounds__(256) void loss_kernel(const unsigned short* __restrict__ Emat,
                                                   const float* __restrict__ logits,
                                                   const float* __restrict__ alpha,
                                                   const float* __restrict__ mpl,
                                                   float* __restrict__ out) {
  const int b = blockIdx.x;
  const ushort8* pe = (const ushort8*)(Emat + (size_t)b * K_DIM) + threadIdx.x * 2;
  const floatv4* pl = (const floatv4*)(logits + (size_t)b * K_DIM) + threadIdx.x * 4;
  const floatv4* pa = (const floatv4*)alpha + threadIdx.x * 4;
  ushort8 e0 = pe[0], e1 = pe[1];
  floatv4 l0 = pl[0], l1 = pl[1], l2 = pl[2], l3 = pl[3];
  floatv4 a0 = pa[0], a1 = pa[1], a2 = pa[2], a3 = pa[3];
  float num = 0.f, den = 0.f;
#pragma unroll
  for (int j = 0; j < 4; ++j) {
    float ea;
    ea = bf2f(e0[j])     * a0[j]; den += ea; num += ea * l0[j];
    ea = bf2f(e0[4 + j]) * a1[j]; den += ea; num += ea * l1[j];
    ea = bf2f(e1[j])     * a2[j]; den += ea; num += ea * l2[j];
    ea = bf2f(e1[4 + j]) * a3[j]; den += ea; num += ea * l3[j];
  }
  __shared__ float sm[8];
  float DEN = blk_sum(den, sm);
  float NUM = blk_sum(num, sm);
  if (threadIdx.x == 0) atomicAdd(out, (mpl[b] - NUM / DEN) * (1.0f / (float)B_DIM));
}

extern "C" void kernel_launch(void* const* d_in, const int* in_sizes, int n_in,
                              void* d_out, int out_size, void* d_ws, size_t ws_size,
                              hipStream_t stream) {
  (void)in_sizes; (void)n_in; (void)out_size; (void)ws_size;
  const float* feat   = (const float*)d_in[0];  // [8192,1024]
  const float* protos = (const float*)d_in[1];  // [4096,1024]
  const float* logits = (const float*)d_in[2];  // [8192,4096]
  float* out = (float*)d_out;

  char* ws = (char*)d_ws;
  // layout (bytes):
  float*          tbuf  = (float*)(ws + 0);                 // 3*4096 f32 (zeroed)
  float*          alpha = (float*)(ws + 49152);             // 4096 f32
  float*          beta  = (float*)(ws + 65536);             // 8192 f32
  float*          mpl   = (float*)(ws + 98304);             // 8192 f32
  unsigned short* wbf   = (unsigned short*)(ws + 131072);   // 4096*1024 bf16
  unsigned short* fbf   = (unsigned short*)(ws + 8519680);  // 8192*1024 bf16
  unsigned short* Emat  = (unsigned short*)(ws + 25296896); // 8192*4096 bf16

  hipMemsetAsync(d_out, 0, sizeof(float), stream);
  hipMemsetAsync(tbuf, 0, 3 * K_DIM * sizeof(float), stream);

  cvt_kernel<<<(B_DIM * D_DIM) / (256 * 4), 256, 0, stream>>>(feat, fbf);
  protonorm_kernel<<<K_DIM, 256, 0, stream>>>(protos, wbf);
  lse_kernel<<<B_DIM, 256, 0, stream>>>(logits, mpl);
  gemm_exp_kernel<<<dim3(B_DIM / 128, K_DIM / 128), 256, 0, stream>>>(fbf, wbf, Emat);

  // Sinkhorn (alpha/beta factored; beta cancels in final normalization)
  row_kernel<1><<<B_DIM, 256, 0, stream>>>(Emat, nullptr, beta);          // init col-norm
  col_kernel<<<dim3(K_DIM / 2048, B_DIM / 64), 256, 0, stream>>>(Emat, beta, tbuf);
  alpha_kernel<1><<<K_DIM / 256, 256, 0, stream>>>(tbuf, alpha);          // iter1 u
  row_kernel<0><<<B_DIM, 256, 0, stream>>>(Emat, alpha, beta);            // iter1 v
  col_kernel<<<dim3(K_DIM / 2048, B_DIM / 64), 256, 0, stream>>>(Emat, beta, tbuf + K_DIM);
  alpha_kernel<0><<<K_DIM / 256, 256, 0, stream>>>(tbuf + K_DIM, alpha);  // iter2 u
  row_kernel<0><<<B_DIM, 256, 0, stream>>>(Emat, alpha, beta);            // iter2 v
  col_kernel<<<dim3(K_DIM / 2048, B_DIM / 64), 256, 0, stream>>>(Emat, beta, tbuf + 2 * K_DIM);
  alpha_kernel<0><<<K_DIM / 256, 256, 0, stream>>>(tbuf + 2 * K_DIM, alpha); // iter3 u
  // iter3 v and final col-norm cancel in the loss -> skip

  loss_kernel<<<B_DIM, 256, 0, stream>>>(Emat, logits, alpha, mpl, out);
}

// Round 3
// 465.450 us; speedup vs baseline: 1.2428x; 1.2428x over previous
//
#include <hip/hip_runtime.h>
#include <hip/hip_bf16.h>
#include <stdint.h>

// Problem constants (from reference setup_inputs)
#define B_DIM 8192
#define K_DIM 4096
#define D_DIM 1024

constexpr float TINY_F = 1e-8f;
constexpr float R_K   = 1.0f / (float)K_DIM;   // row marginal 1/K
constexpr float C_B   = 1.0f / (float)B_DIM;   // col marginal 1/B
constexpr float SCALE = 1.0f / (0.01f * 0.7f); // 1/(TEMPERATURE*EPSILON)

typedef __attribute__((ext_vector_type(8))) short     short8;   // 8 bf16 (MFMA frag)
typedef __attribute__((ext_vector_type(8))) unsigned short ushort8;
typedef __attribute__((ext_vector_type(4))) unsigned short ushort4v;
typedef __attribute__((ext_vector_type(4))) float     f32x4;
typedef __attribute__((ext_vector_type(4))) float     floatv4;

__device__ __forceinline__ float bf2f(unsigned short u) {
  return __builtin_bit_cast(float, (unsigned int)u << 16);
}
__device__ __forceinline__ unsigned short f2bf(float f) {
  unsigned int x = __builtin_bit_cast(unsigned int, f);
  x += 0x7FFFu + ((x >> 16) & 1u);  // round-to-nearest-even (no NaN inputs here)
  return (unsigned short)(x >> 16);
}

// ---- block reductions (256 threads = 4 waves of 64) ----
__device__ __forceinline__ float blk_sum(float v, float* sm) {
#pragma unroll
  for (int m = 32; m > 0; m >>= 1) v += __shfl_xor(v, m);
  if ((threadIdx.x & 63) == 0) sm[threadIdx.x >> 6] = v;
  __syncthreads();
  float r = sm[0] + sm[1] + sm[2] + sm[3];
  __syncthreads();
  return r;
}

// ---- f32 -> bf16 convert (features) ----
__global__ __launch_bounds__(256) void cvt_kernel(const float* __restrict__ in,
                                                  unsigned short* __restrict__ out) {
  const int i = (blockIdx.x * 256 + threadIdx.x) * 4;
  floatv4 v = *(const floatv4*)(in + i);
  ushort4v o = { f2bf(v[0]), f2bf(v[1]), f2bf(v[2]), f2bf(v[3]) };
  *(ushort4v*)(out + i) = o;
}

// ---- row-normalize prototypes -> bf16 ----
__global__ __launch_bounds__(256) void protonorm_kernel(const float* __restrict__ w,
                                                        unsigned short* __restrict__ wbf) {
  const int k = blockIdx.x;
  const floatv4* pr = (const floatv4*)(w + (size_t)k * D_DIM) + threadIdx.x;
  floatv4 v = *pr;
  float ss = v[0]*v[0] + v[1]*v[1] + v[2]*v[2] + v[3]*v[3];
  __shared__ float sm[8];
  float tot = blk_sum(ss, sm);
  float inv = 1.0f / sqrtf(tot);
  ushort4v o = { f2bf(v[0]*inv), f2bf(v[1]*inv), f2bf(v[2]*inv), f2bf(v[3]*inv) };
  *((ushort4v*)(wbf + (size_t)k * D_DIM) + threadIdx.x) = o;
}

// ---- GEMM: E[b,k] = exp( (feat_b . w_k) * SCALE ), bf16 output ----
// 128x128 tile, BK=32, 4 waves (2x2), 16x16x32 bf16 MFMA, global_load_lds width16.
__device__ __forceinline__ void gload_lds16(const unsigned short* g, unsigned short* l) {
  __builtin_amdgcn_global_load_lds(
      (const __attribute__((address_space(1))) void*)g,
      (__attribute__((address_space(3))) void*)l, 16, 0, 0);
}

__global__ __launch_bounds__(256) void gemm_exp_kernel(const unsigned short* __restrict__ fbf,
                                                       const unsigned short* __restrict__ wbf,
                                                       unsigned short* __restrict__ Emat) {
  __shared__ unsigned short sA[128 * 32];
  __shared__ unsigned short sB[128 * 32];
  const int tid  = threadIdx.x;
  const int lane = tid & 63;
  const int wid  = tid >> 6;
  const int wr = wid >> 1, wc = wid & 1;
  const int m0 = blockIdx.x * 128;
  const int n0 = blockIdx.y * 128;

  f32x4 acc[4][4];
#pragma unroll
  for (int i = 0; i < 4; ++i)
#pragma unroll
    for (int j = 0; j < 4; ++j) acc[i][j] = (f32x4){0.f, 0.f, 0.f, 0.f};

  // staging: 8 chunks of 16 rows x 32 cols per matrix; wave w owns chunks 2w, 2w+1
  const int srow = (wid * 2) * 16 + (lane >> 2);
  const int scol = (lane & 3) * 8;
  const unsigned short* ga0 = fbf + (size_t)(m0 + srow) * D_DIM + scol;
  const unsigned short* gb0 = wbf + (size_t)(n0 + srow) * D_DIM + scol;
  unsigned short* la0 = &sA[(wid * 2) * 512];
  unsigned short* lb0 = &sB[(wid * 2) * 512];

  const int fr = lane & 15;
  const int fk = (lane >> 4) * 8;

  for (int kt = 0; kt < D_DIM / 32; ++kt) {
    const int kk = kt * 32;
    if (kt) __syncthreads();
    gload_lds16(ga0 + kk,              la0);
    gload_lds16(ga0 + 16 * D_DIM + kk, la0 + 512);
    gload_lds16(gb0 + kk,              lb0);
    gload_lds16(gb0 + 16 * D_DIM + kk, lb0 + 512);
    __syncthreads();  // compiler emits vmcnt(0) before barrier

    short8 af[4], bfr[4];
#pragma unroll
    for (int mi = 0; mi < 4; ++mi)
      af[mi] = *(const short8*)&sA[(wr * 64 + mi * 16 + fr) * 32 + fk];
#pragma unroll
    for (int ni = 0; ni < 4; ++ni)
      bfr[ni] = *(const short8*)&sB[(wc * 64 + ni * 16 + fr) * 32 + fk];
#pragma unroll
    for (int mi = 0; mi < 4; ++mi)
#pragma unroll
      for (int ni = 0; ni < 4; ++ni)
        acc[mi][ni] = __builtin_amdgcn_mfma_f32_16x16x32_bf16(af[mi], bfr[ni], acc[mi][ni], 0, 0, 0);
  }

  // epilogue: C/D layout col=lane&15, row=(lane>>4)*4+reg
  const int fq = lane >> 4;
#pragma unroll
  for (int mi = 0; mi < 4; ++mi) {
#pragma unroll
    for (int r = 0; r < 4; ++r) {
      const int row = m0 + wr * 64 + mi * 16 + fq * 4 + r;
      const size_t base = (size_t)row * K_DIM + n0 + wc * 64 + fr;
#pragma unroll
      for (int ni = 0; ni < 4; ++ni) {
        float z = acc[mi][ni][r] * SCALE;
        Emat[base + ni * 16] = f2bf(__expf(z));
      }
    }
  }
}

// ---- row pass: s[b] = sum_k E[b,k]*alpha[k]; INIT: beta=1/s ; else beta *= c/(beta*s+TINY) ----
template <int INIT>
__global__ __launch_bounds__(256) void row_kernel(const unsigned short* __restrict__ Emat,
                                                  const float* __restrict__ alpha,
                                                  float* __restrict__ beta) {
  const int b = blockIdx.x;
  const ushort8* pe = (const ushort8*)(Emat + (size_t)b * K_DIM) + threadIdx.x * 2;
  ushort8 e0 = pe[0], e1 = pe[1];
  float s = 0.f;
  if (INIT) {
#pragma unroll
    for (int j = 0; j < 8; ++j) s += bf2f(e0[j]) + bf2f(e1[j]);
  } else {
    const floatv4* pa = (const floatv4*)alpha + threadIdx.x * 4;
    floatv4 a0 = pa[0], a1 = pa[1], a2 = pa[2], a3 = pa[3];
#pragma unroll
    for (int j = 0; j < 4; ++j) {
      s += bf2f(e0[j])     * a0[j];
      s += bf2f(e0[4 + j]) * a1[j];
      s += bf2f(e1[j])     * a2[j];
      s += bf2f(e1[4 + j]) * a3[j];
    }
  }
  __shared__ float sm[8];
  float tot = blk_sum(s, sm);
  if (threadIdx.x == 0) {
    if (INIT) {
      beta[b] = 1.0f / tot;
    } else {
      float bb = beta[b];
      float v  = bb * tot;
      beta[b]  = bb * (C_B / (v + TINY_F));
    }
  }
}

// ---- col pass: t[k] += sum_b E[b,k]*beta[b] over a 64-row chunk ----
__global__ __launch_bounds__(256) void col_kernel(const unsigned short* __restrict__ Emat,
                                                  const float* __restrict__ beta,
                                                  float* __restrict__ tbuf) {
  const int k0 = (blockIdx.x * 256 + threadIdx.x) * 8;
  const int b0 = blockIdx.y * 64;
  const ushort8* p = (const ushort8*)(Emat + (size_t)b0 * K_DIM + k0);
  float acc[8] = {0.f, 0.f, 0.f, 0.f, 0.f, 0.f, 0.f, 0.f};
  for (int i = 0; i < 64; ++i) {
    ushort8 e = p[(size_t)i * (K_DIM / 8)];
    float bb = beta[b0 + i];
#pragma unroll
    for (int j = 0; j < 8; ++j) acc[j] = fmaf(bf2f(e[j]), bb, acc[j]);
  }
#pragma unroll
  for (int j = 0; j < 8; ++j) atomicAdd(&tbuf[k0 + j], acc[j]);
}

// ---- alpha update: u = alpha*t; alpha *= r/(u+TINY) (FIRST: alpha was 1) ----
template <int FIRST>
__global__ __launch_bounds__(256) void alpha_kernel(const float* __restrict__ tbuf,
                                                    float* __restrict__ alpha) {
  const int k = blockIdx.x * 256 + threadIdx.x;
  float t = tbuf[k];
  if (FIRST) {
    alpha[k] = R_K / (t + TINY_F);
  } else {
    float a = alpha[k];
    alpha[k] = a * R_K / (a * t + TINY_F);
  }
}

// ---- fused lse+loss per row: contrib[b] = (max+log(sum exp)) - (sum Ea*logits)/(sum Ea) ----
__global__ __launch_bounds__(256) void loss_row_kernel(const unsigned short* __restrict__ Emat,
                                                       const float* __restrict__ logits,
                                                       const float* __restrict__ alpha,
                                                       float* __restrict__ contrib) {
  const int b = blockIdx.x;
  const floatv4* pl = (const floatv4*)(logits + (size_t)b * K_DIM) + threadIdx.x * 4;
  floatv4 l0 = pl[0], l1 = pl[1], l2 = pl[2], l3 = pl[3];
  const ushort8* pe = (const ushort8*)(Emat + (size_t)b * K_DIM) + threadIdx.x * 2;
  ushort8 e0 = pe[0], e1 = pe[1];
  const floatv4* pa = (const floatv4*)alpha + threadIdx.x * 4;
  floatv4 a0 = pa[0], a1 = pa[1], a2 = pa[2], a3 = pa[3];

  // reduction 1: row max of logits
  float m = l0[0];
#pragma unroll
  for (int j = 0; j < 4; ++j) {
    m = fmaxf(m, l0[j]); m = fmaxf(m, l1[j]);
    m = fmaxf(m, l2[j]); m = fmaxf(m, l3[j]);
  }
#pragma unroll
  for (int mm = 32; mm > 0; mm >>= 1) m = fmaxf(m, __shfl_xor(m, mm));
  __shared__ float smx[4];
  __shared__ float sm3[12];
  if ((threadIdx.x & 63) == 0) smx[threadIdx.x >> 6] = m;
  __syncthreads();
  const float M = fmaxf(fmaxf(smx[0], smx[1]), fmaxf(smx[2], smx[3]));

  // partials: s = sum exp(l-M); den = sum E*alpha; num = sum E*alpha*l
  float s = 0.f, num = 0.f, den = 0.f;
#pragma unroll
  for (int j = 0; j < 4; ++j) {
    s += __expf(l0[j] - M) + __expf(l1[j] - M) + __expf(l2[j] - M) + __expf(l3[j] - M);
    float ea;
    ea = bf2f(e0[j])     * a0[j]; den += ea; num += ea * l0[j];
    ea = bf2f(e0[4 + j]) * a1[j]; den += ea; num += ea * l1[j];
    ea = bf2f(e1[j])     * a2[j]; den += ea; num += ea * l2[j];
    ea = bf2f(e1[4 + j]) * a3[j]; den += ea; num += ea * l3[j];
  }
  // reduction 2: joint sum of (s, num, den)
#pragma unroll
  for (int mm = 32; mm > 0; mm >>= 1) {
    s   += __shfl_xor(s, mm);
    num += __shfl_xor(num, mm);
    den += __shfl_xor(den, mm);
  }
  const int w = threadIdx.x >> 6;
  if ((threadIdx.x & 63) == 0) { sm3[w] = s; sm3[4 + w] = num; sm3[8 + w] = den; }
  __syncthreads();
  if (threadIdx.x == 0) {
    float S   = sm3[0] + sm3[1] + sm3[2]  + sm3[3];
    float NUM = sm3[4] + sm3[5] + sm3[6]  + sm3[7];
    float DEN = sm3[8] + sm3[9] + sm3[10] + sm3[11];
    contrib[b] = (M + __logf(S)) - NUM / DEN;
  }
}

// ---- final: out = mean(contrib) ----
__global__ __launch_bounds__(256) void final_reduce_kernel(const float* __restrict__ contrib,
                                                           float* __restrict__ out) {
  float s = 0.f;
  const floatv4* p = (const floatv4*)contrib + threadIdx.x;
#pragma unroll
  for (int i = 0; i < 8; ++i) {
    floatv4 v = p[i * 256];
    s += v[0] + v[1] + v[2] + v[3];
  }
  __shared__ float sm[8];
  float tot = blk_sum(s, sm);
  if (threadIdx.x == 0) *out = tot * (1.0f / (float)B_DIM);
}

extern "C" void kernel_launch(void* const* d_in, const int* in_sizes, int n_in,
                              void* d_out, int out_size, void* d_ws, size_t ws_size,
                              hipStream_t stream) {
  (void)in_sizes; (void)n_in; (void)out_size; (void)ws_size;
  const float* feat   = (const float*)d_in[0];  // [8192,1024]
  const float* protos = (const float*)d_in[1];  // [4096,1024]
  const float* logits = (const float*)d_in[2];  // [8192,4096]
  float* out = (float*)d_out;

  char* ws = (char*)d_ws;
  // layout (bytes):
  float*          tbuf    = (float*)(ws + 0);                 // 3*4096 f32 (zeroed)
  float*          alpha   = (float*)(ws + 49152);             // 4096 f32
  float*          beta    = (float*)(ws + 65536);             // 8192 f32
  float*          contrib = (float*)(ws + 98304);             // 8192 f32
  unsigned short* wbf     = (unsigned short*)(ws + 131072);   // 4096*1024 bf16
  unsigned short* fbf     = (unsigned short*)(ws + 8519680);  // 8192*1024 bf16
  unsigned short* Emat    = (unsigned short*)(ws + 25296896); // 8192*4096 bf16

  hipMemsetAsync(tbuf, 0, 3 * K_DIM * sizeof(float), stream);

  cvt_kernel<<<(B_DIM * D_DIM) / (256 * 4), 256, 0, stream>>>(feat, fbf);
  protonorm_kernel<<<K_DIM, 256, 0, stream>>>(protos, wbf);
  gemm_exp_kernel<<<dim3(B_DIM / 128, K_DIM / 128), 256, 0, stream>>>(fbf, wbf, Emat);

  // Sinkhorn (alpha/beta factored; beta cancels in final normalization)
  row_kernel<1><<<B_DIM, 256, 0, stream>>>(Emat, nullptr, beta);          // init col-norm
  col_kernel<<<dim3(K_DIM / 2048, B_DIM / 64), 256, 0, stream>>>(Emat, beta, tbuf);
  alpha_kernel<1><<<K_DIM / 256, 256, 0, stream>>>(tbuf, alpha);          // iter1 u
  row_kernel<0><<<B_DIM, 256, 0, stream>>>(Emat, alpha, beta);            // iter1 v
  col_kernel<<<dim3(K_DIM / 2048, B_DIM / 64), 256, 0, stream>>>(Emat, beta, tbuf + K_DIM);
  alpha_kernel<0><<<K_DIM / 256, 256, 0, stream>>>(tbuf + K_DIM, alpha);  // iter2 u
  row_kernel<0><<<B_DIM, 256, 0, stream>>>(Emat, alpha, beta);            // iter2 v
  col_kernel<<<dim3(K_DIM / 2048, B_DIM / 64), 256, 0, stream>>>(Emat, beta, tbuf + 2 * K_DIM);
  alpha_kernel<0><<<K_DIM / 256, 256, 0, stream>>>(tbuf + 2 * K_DIM, alpha); // iter3 u
  // iter3 v and final col-norm cancel in the loss -> skip

  loss_row_kernel<<<B_DIM, 256, 0, stream>>>(Emat, logits, alpha, contrib);
  final_reduce_kernel<<<1, 256, 0, stream>>>(contrib, out);
}

// Round 4
// 445.483 us; speedup vs baseline: 1.2985x; 1.0448x over previous
//
#include <hip/hip_runtime.h>
#include <hip/hip_bf16.h>
#include <stdint.h>

// Problem constants (from reference setup_inputs)
#define B_DIM 8192
#define K_DIM 4096
#define D_DIM 1024

constexpr float TINY_F = 1e-8f;
constexpr float R_K   = 1.0f / (float)K_DIM;   // row marginal 1/K
constexpr float C_B   = 1.0f / (float)B_DIM;   // col marginal 1/B
constexpr float SCALE = 1.0f / (0.01f * 0.7f); // 1/(TEMPERATURE*EPSILON)

typedef __attribute__((ext_vector_type(8))) short     short8;   // 8 bf16 (MFMA frag)
typedef __attribute__((ext_vector_type(8))) unsigned short ushort8;
typedef __attribute__((ext_vector_type(4))) unsigned short ushort4v;
typedef __attribute__((ext_vector_type(4))) float     f32x4;
typedef __attribute__((ext_vector_type(4))) float     floatv4;

__device__ __forceinline__ float bf2f(unsigned short u) {
  return __builtin_bit_cast(float, (unsigned int)u << 16);
}
__device__ __forceinline__ unsigned short f2bf(float f) {
  unsigned int x = __builtin_bit_cast(unsigned int, f);
  x += 0x7FFFu + ((x >> 16) & 1u);  // round-to-nearest-even (no NaN inputs here)
  return (unsigned short)(x >> 16);
}

// ---- block reductions (256 threads = 4 waves of 64) ----
__device__ __forceinline__ float blk_sum(float v, float* sm) {
#pragma unroll
  for (int m = 32; m > 0; m >>= 1) v += __shfl_xor(v, m);
  if ((threadIdx.x & 63) == 0) sm[threadIdx.x >> 6] = v;
  __syncthreads();
  float r = sm[0] + sm[1] + sm[2] + sm[3];
  __syncthreads();
  return r;
}

// ---- f32 -> bf16 convert (features) ----
__global__ __launch_bounds__(256) void cvt_kernel(const float* __restrict__ in,
                                                  unsigned short* __restrict__ out) {
  const int i = (blockIdx.x * 256 + threadIdx.x) * 4;
  floatv4 v = *(const floatv4*)(in + i);
  ushort4v o = { f2bf(v[0]), f2bf(v[1]), f2bf(v[2]), f2bf(v[3]) };
  *(ushort4v*)(out + i) = o;
}

// ---- row-normalize prototypes -> bf16 ----
__global__ __launch_bounds__(256) void protonorm_kernel(const float* __restrict__ w,
                                                        unsigned short* __restrict__ wbf) {
  const int k = blockIdx.x;
  const floatv4* pr = (const floatv4*)(w + (size_t)k * D_DIM) + threadIdx.x;
  floatv4 v = *pr;
  float ss = v[0]*v[0] + v[1]*v[1] + v[2]*v[2] + v[3]*v[3];
  __shared__ float sm[8];
  float tot = blk_sum(ss, sm);
  float inv = 1.0f / sqrtf(tot);
  ushort4v o = { f2bf(v[0]*inv), f2bf(v[1]*inv), f2bf(v[2]*inv), f2bf(v[3]*inv) };
  *((ushort4v*)(wbf + (size_t)k * D_DIM) + threadIdx.x) = o;
}

// ---- GEMM: E[b,k] = exp( (feat_b . w_k) * SCALE ), bf16 output ----
// 128x128 tile, BK=32, 4 waves (2x2), 16x16x32 bf16 MFMA, global_load_lds width16.
// Fused: per-row sums of exp() atomicAdd'ed into rowsum[] (replaces init row pass).
__device__ __forceinline__ void gload_lds16(const unsigned short* g, unsigned short* l) {
  __builtin_amdgcn_global_load_lds(
      (const __attribute__((address_space(1))) void*)g,
      (__attribute__((address_space(3))) void*)l, 16, 0, 0);
}

__global__ __launch_bounds__(256) void gemm_exp_kernel(const unsigned short* __restrict__ fbf,
                                                       const unsigned short* __restrict__ wbf,
                                                       unsigned short* __restrict__ Emat,
                                                       float* __restrict__ rowsum) {
  __shared__ unsigned short sA[128 * 32];
  __shared__ unsigned short sB[128 * 32];
  const int tid  = threadIdx.x;
  const int lane = tid & 63;
  const int wid  = tid >> 6;
  const int wr = wid >> 1, wc = wid & 1;
  const int m0 = blockIdx.x * 128;
  const int n0 = blockIdx.y * 128;

  f32x4 acc[4][4];
#pragma unroll
  for (int i = 0; i < 4; ++i)
#pragma unroll
    for (int j = 0; j < 4; ++j) acc[i][j] = (f32x4){0.f, 0.f, 0.f, 0.f};

  // staging: 8 chunks of 16 rows x 32 cols per matrix; wave w owns chunks 2w, 2w+1
  const int srow = (wid * 2) * 16 + (lane >> 2);
  const int scol = (lane & 3) * 8;
  const unsigned short* ga0 = fbf + (size_t)(m0 + srow) * D_DIM + scol;
  const unsigned short* gb0 = wbf + (size_t)(n0 + srow) * D_DIM + scol;
  unsigned short* la0 = &sA[(wid * 2) * 512];
  unsigned short* lb0 = &sB[(wid * 2) * 512];

  const int fr = lane & 15;
  const int fk = (lane >> 4) * 8;

  for (int kt = 0; kt < D_DIM / 32; ++kt) {
    const int kk = kt * 32;
    if (kt) __syncthreads();
    gload_lds16(ga0 + kk,              la0);
    gload_lds16(ga0 + 16 * D_DIM + kk, la0 + 512);
    gload_lds16(gb0 + kk,              lb0);
    gload_lds16(gb0 + 16 * D_DIM + kk, lb0 + 512);
    __syncthreads();  // compiler emits vmcnt(0) before barrier

    short8 af[4], bfr[4];
#pragma unroll
    for (int mi = 0; mi < 4; ++mi)
      af[mi] = *(const short8*)&sA[(wr * 64 + mi * 16 + fr) * 32 + fk];
#pragma unroll
    for (int ni = 0; ni < 4; ++ni)
      bfr[ni] = *(const short8*)&sB[(wc * 64 + ni * 16 + fr) * 32 + fk];
#pragma unroll
    for (int mi = 0; mi < 4; ++mi)
#pragma unroll
      for (int ni = 0; ni < 4; ++ni)
        acc[mi][ni] = __builtin_amdgcn_mfma_f32_16x16x32_bf16(af[mi], bfr[ni], acc[mi][ni], 0, 0, 0);
  }

  // epilogue: C/D layout col=lane&15, row=(lane>>4)*4+reg
  const int fq = lane >> 4;
#pragma unroll
  for (int mi = 0; mi < 4; ++mi) {
#pragma unroll
    for (int r = 0; r < 4; ++r) {
      const int row = m0 + wr * 64 + mi * 16 + fq * 4 + r;
      const size_t base = (size_t)row * K_DIM + n0 + wc * 64 + fr;
      float ps = 0.f;
#pragma unroll
      for (int ni = 0; ni < 4; ++ni) {
        float ev = __expf(acc[mi][ni][r] * SCALE);
        Emat[base + ni * 16] = f2bf(ev);
        ps += ev;
      }
      // reduce across the 16 lanes (fr=0..15) sharing this row
      ps += __shfl_xor(ps, 1); ps += __shfl_xor(ps, 2);
      ps += __shfl_xor(ps, 4); ps += __shfl_xor(ps, 8);
      if (fr == 0) atomicAdd(&rowsum[row], ps);
    }
  }
}

// ---- beta init: beta[b] = 1/rowsum[b] (Q column-normalization factor) ----
__global__ __launch_bounds__(256) void beta_init_kernel(const float* __restrict__ rowsum,
                                                        float* __restrict__ beta) {
  const int b = blockIdx.x * 256 + threadIdx.x;
  beta[b] = 1.0f / rowsum[b];
}

// ---- row pass: s[b] = sum_k E[b,k]*alpha[k]; beta *= c/(beta*s+TINY) ----
__global__ __launch_bounds__(256) void row_kernel(const unsigned short* __restrict__ Emat,
                                                  const float* __restrict__ alpha,
                                                  float* __restrict__ beta) {
  const int b = blockIdx.x;
  const ushort8* pe = (const ushort8*)(Emat + (size_t)b * K_DIM) + threadIdx.x * 2;
  ushort8 e0 = pe[0], e1 = pe[1];
  float s = 0.f;
  const floatv4* pa = (const floatv4*)alpha + threadIdx.x * 4;
  floatv4 a0 = pa[0], a1 = pa[1], a2 = pa[2], a3 = pa[3];
#pragma unroll
  for (int j = 0; j < 4; ++j) {
    s += bf2f(e0[j])     * a0[j];
    s += bf2f(e0[4 + j]) * a1[j];
    s += bf2f(e1[j])     * a2[j];
    s += bf2f(e1[4 + j]) * a3[j];
  }
  __shared__ float sm[8];
  float tot = blk_sum(s, sm);
  if (threadIdx.x == 0) {
    float bb = beta[b];
    float v  = bb * tot;
    beta[b]  = bb * (C_B / (v + TINY_F));
  }
}

// ---- col pass: t[k] += sum_b E[b,k]*beta[b] over a 64-row chunk ----
// grid (K/512, B/64) = (8,128) = 1024 blocks (4/CU). Wave-group wg handles 16 rows;
// 4 wave-groups reduced in LDS -> one atomicAdd per k per block.
__global__ __launch_bounds__(256) void col_kernel(const unsigned short* __restrict__ Emat,
                                                  const float* __restrict__ beta,
                                                  float* __restrict__ tbuf) {
  const int lane = threadIdx.x & 63;
  const int wg   = threadIdx.x >> 6;
  const int k0 = blockIdx.x * 512 + lane * 8;
  const int b0 = blockIdx.y * 64 + wg * 16;
  const ushort8* p = (const ushort8*)(Emat + (size_t)b0 * K_DIM + k0);
  float acc[8] = {0.f, 0.f, 0.f, 0.f, 0.f, 0.f, 0.f, 0.f};
#pragma unroll
  for (int i = 0; i < 16; ++i) {
    ushort8 e = p[(size_t)i * (K_DIM / 8)];
    float bb = beta[b0 + i];
#pragma unroll
    for (int j = 0; j < 8; ++j) acc[j] = fmaf(bf2f(e[j]), bb, acc[j]);
  }
  __shared__ float red[3][512];
  if (wg > 0) {
#pragma unroll
    for (int j = 0; j < 8; ++j) red[wg - 1][lane * 8 + j] = acc[j];
  }
  __syncthreads();
  if (wg == 0) {
#pragma unroll
    for (int j = 0; j < 8; ++j) {
      float s = acc[j] + red[0][lane * 8 + j] + red[1][lane * 8 + j] + red[2][lane * 8 + j];
      atomicAdd(&tbuf[k0 + j], s);
    }
  }
}

// ---- alpha update: u = alpha*t; alpha *= r/(u+TINY) (FIRST: alpha was 1) ----
template <int FIRST>
__global__ __launch_bounds__(256) void alpha_kernel(const float* __restrict__ tbuf,
                                                    float* __restrict__ alpha) {
  const int k = blockIdx.x * 256 + threadIdx.x;
  float t = tbuf[k];
  if (FIRST) {
    alpha[k] = R_K / (t + TINY_F);
  } else {
    float a = alpha[k];
    alpha[k] = a * R_K / (a * t + TINY_F);
  }
}

// ---- fused lse+loss per row: contrib[b] = (max+log(sum exp)) - (sum Ea*logits)/(sum Ea) ----
__global__ __launch_bounds__(256) void loss_row_kernel(const unsigned short* __restrict__ Emat,
                                                       const float* __restrict__ logits,
                                                       const float* __restrict__ alpha,
                                                       float* __restrict__ contrib) {
  const int b = blockIdx.x;
  const floatv4* pl = (const floatv4*)(logits + (size_t)b * K_DIM) + threadIdx.x * 4;
  floatv4 l0 = pl[0], l1 = pl[1], l2 = pl[2], l3 = pl[3];
  const ushort8* pe = (const ushort8*)(Emat + (size_t)b * K_DIM) + threadIdx.x * 2;
  ushort8 e0 = pe[0], e1 = pe[1];
  const floatv4* pa = (const floatv4*)alpha + threadIdx.x * 4;
  floatv4 a0 = pa[0], a1 = pa[1], a2 = pa[2], a3 = pa[3];

  // reduction 1: row max of logits
  float m = l0[0];
#pragma unroll
  for (int j = 0; j < 4; ++j) {
    m = fmaxf(m, l0[j]); m = fmaxf(m, l1[j]);
    m = fmaxf(m, l2[j]); m = fmaxf(m, l3[j]);
  }
#pragma unroll
  for (int mm = 32; mm > 0; mm >>= 1) m = fmaxf(m, __shfl_xor(m, mm));
  __shared__ float smx[4];
  __shared__ float sm3[12];
  if ((threadIdx.x & 63) == 0) smx[threadIdx.x >> 6] = m;
  __syncthreads();
  const float M = fmaxf(fmaxf(smx[0], smx[1]), fmaxf(smx[2], smx[3]));

  // partials: s = sum exp(l-M); den = sum E*alpha; num = sum E*alpha*l
  float s = 0.f, num = 0.f, den = 0.f;
#pragma unroll
  for (int j = 0; j < 4; ++j) {
    s += __expf(l0[j] - M) + __expf(l1[j] - M) + __expf(l2[j] - M) + __expf(l3[j] - M);
    float ea;
    ea = bf2f(e0[j])     * a0[j]; den += ea; num += ea * l0[j];
    ea = bf2f(e0[4 + j]) * a1[j]; den += ea; num += ea * l1[j];
    ea = bf2f(e1[j])     * a2[j]; den += ea; num += ea * l2[j];
    ea = bf2f(e1[4 + j]) * a3[j]; den += ea; num += ea * l3[j];
  }
  // reduction 2: joint sum of (s, num, den)
#pragma unroll
  for (int mm = 32; mm > 0; mm >>= 1) {
    s   += __shfl_xor(s, mm);
    num += __shfl_xor(num, mm);
    den += __shfl_xor(den, mm);
  }
  const int w = threadIdx.x >> 6;
  if ((threadIdx.x & 63) == 0) { sm3[w] = s; sm3[4 + w] = num; sm3[8 + w] = den; }
  __syncthreads();
  if (threadIdx.x == 0) {
    float S   = sm3[0] + sm3[1] + sm3[2]  + sm3[3];
    float NUM = sm3[4] + sm3[5] + sm3[6]  + sm3[7];
    float DEN = sm3[8] + sm3[9] + sm3[10] + sm3[11];
    contrib[b] = (M + __logf(S)) - NUM / DEN;
  }
}

// ---- final: out = mean(contrib) ----
__global__ __launch_bounds__(256) void final_reduce_kernel(const float* __restrict__ contrib,
                                                           float* __restrict__ out) {
  float s = 0.f;
  const floatv4* p = (const floatv4*)contrib + threadIdx.x;
#pragma unroll
  for (int i = 0; i < 8; ++i) {
    floatv4 v = p[i * 256];
    s += v[0] + v[1] + v[2] + v[3];
  }
  __shared__ float sm[8];
  float tot = blk_sum(s, sm);
  if (threadIdx.x == 0) *out = tot * (1.0f / (float)B_DIM);
}

extern "C" void kernel_launch(void* const* d_in, const int* in_sizes, int n_in,
                              void* d_out, int out_size, void* d_ws, size_t ws_size,
                              hipStream_t stream) {
  (void)in_sizes; (void)n_in; (void)out_size; (void)ws_size;
  const float* feat   = (const float*)d_in[0];  // [8192,1024]
  const float* protos = (const float*)d_in[1];  // [4096,1024]
  const float* logits = (const float*)d_in[2];  // [8192,4096]
  float* out = (float*)d_out;

  char* ws = (char*)d_ws;
  // layout (bytes):
  float*          tbuf    = (float*)(ws + 0);                 // 3*4096 f32 (zeroed)
  float*          rowsum  = (float*)(ws + 49152);             // 8192 f32 (zeroed)
  float*          alpha   = (float*)(ws + 81920);             // 4096 f32
  float*          beta    = (float*)(ws + 98304);             // 8192 f32
  float*          contrib = (float*)(ws + 131072);            // 8192 f32
  unsigned short* wbf     = (unsigned short*)(ws + 163840);   // 4096*1024 bf16
  unsigned short* fbf     = (unsigned short*)(ws + 8552448);  // 8192*1024 bf16
  unsigned short* Emat    = (unsigned short*)(ws + 25329664); // 8192*4096 bf16

  hipMemsetAsync(ws, 0, 81920, stream);  // tbuf + rowsum

  cvt_kernel<<<(B_DIM * D_DIM) / (256 * 4), 256, 0, stream>>>(feat, fbf);
  protonorm_kernel<<<K_DIM, 256, 0, stream>>>(protos, wbf);
  gemm_exp_kernel<<<dim3(B_DIM / 128, K_DIM / 128), 256, 0, stream>>>(fbf, wbf, Emat, rowsum);
  beta_init_kernel<<<B_DIM / 256, 256, 0, stream>>>(rowsum, beta);

  // Sinkhorn (alpha/beta factored; beta cancels in final normalization)
  col_kernel<<<dim3(K_DIM / 512, B_DIM / 64), 256, 0, stream>>>(Emat, beta, tbuf);
  alpha_kernel<1><<<K_DIM / 256, 256, 0, stream>>>(tbuf, alpha);            // iter1 u
  row_kernel<<<B_DIM, 256, 0, stream>>>(Emat, alpha, beta);                 // iter1 v
  col_kernel<<<dim3(K_DIM / 512, B_DIM / 64), 256, 0, stream>>>(Emat, beta, tbuf + K_DIM);
  alpha_kernel<0><<<K_DIM / 256, 256, 0, stream>>>(tbuf + K_DIM, alpha);    // iter2 u
  row_kernel<<<B_DIM, 256, 0, stream>>>(Emat, alpha, beta);                 // iter2 v
  col_kernel<<<dim3(K_DIM / 512, B_DIM / 64), 256, 0, stream>>>(Emat, beta, tbuf + 2 * K_DIM);
  alpha_kernel<0><<<K_DIM / 256, 256, 0, stream>>>(tbuf + 2 * K_DIM, alpha); // iter3 u
  // iter3 v and final col-norm cancel in the loss -> skip

  loss_row_kernel<<<B_DIM, 256, 0, stream>>>(Emat, logits, alpha, contrib);
  final_reduce_kernel<<<1, 256, 0, stream>>>(contrib, out);
}

// Round 5
// 391.250 us; speedup vs baseline: 1.4785x; 1.1386x over previous
//
#include <hip/hip_runtime.h>
#include <hip/hip_bf16.h>
#include <stdint.h>

// Problem constants (from reference setup_inputs)
#define B_DIM 8192
#define K_DIM 4096
#define D_DIM 1024

constexpr float TINY_F = 1e-8f;
constexpr float R_K   = 1.0f / (float)K_DIM;   // row marginal 1/K
constexpr float C_B   = 1.0f / (float)B_DIM;   // col marginal 1/B
constexpr float SCALE = 1.0f / (0.01f * 0.7f); // 1/(TEMPERATURE*EPSILON)

typedef __attribute__((ext_vector_type(8))) short     short8;   // 8 bf16 (MFMA frag)
typedef __attribute__((ext_vector_type(8))) unsigned short ushort8;
typedef __attribute__((ext_vector_type(4))) unsigned short ushort4v;
typedef __attribute__((ext_vector_type(4))) float     f32x4;
typedef __attribute__((ext_vector_type(4))) float     floatv4;

__device__ __forceinline__ float bf2f(unsigned short u) {
  return __builtin_bit_cast(float, (unsigned int)u << 16);
}
__device__ __forceinline__ unsigned short f2bf(float f) {
  unsigned int x = __builtin_bit_cast(unsigned int, f);
  x += 0x7FFFu + ((x >> 16) & 1u);  // round-to-nearest-even (no NaN inputs here)
  return (unsigned short)(x >> 16);
}

// ---- block reduction (256 threads = 4 waves of 64) ----
__device__ __forceinline__ float blk_sum(float v, float* sm) {
#pragma unroll
  for (int m = 32; m > 0; m >>= 1) v += __shfl_xor(v, m);
  if ((threadIdx.x & 63) == 0) sm[threadIdx.x >> 6] = v;
  __syncthreads();
  float r = sm[0] + sm[1] + sm[2] + sm[3];
  __syncthreads();
  return r;
}

// ---- f32 -> bf16 convert (features): 4 float4 per thread, 2048 blocks ----
__global__ __launch_bounds__(256) void cvt_kernel(const float* __restrict__ in,
                                                  unsigned short* __restrict__ out) {
  const int i0 = blockIdx.x * 1024 + threadIdx.x;  // float4 units
  const floatv4* p = (const floatv4*)in;
#pragma unroll
  for (int q = 0; q < 4; ++q) {
    const int i = i0 + q * 256;
    floatv4 v = p[i];
    ushort4v o = { f2bf(v[0]), f2bf(v[1]), f2bf(v[2]), f2bf(v[3]) };
    *((ushort4v*)out + i) = o;
  }
}

// ---- row-normalize prototypes -> bf16 ----
__global__ __launch_bounds__(256) void protonorm_kernel(const float* __restrict__ w,
                                                        unsigned short* __restrict__ wbf) {
  const int k = blockIdx.x;
  const floatv4* pr = (const floatv4*)(w + (size_t)k * D_DIM) + threadIdx.x;
  floatv4 v = *pr;
  float ss = v[0]*v[0] + v[1]*v[1] + v[2]*v[2] + v[3]*v[3];
  __shared__ float sm[8];
  float tot = blk_sum(ss, sm);
  float inv = 1.0f / sqrtf(tot);
  ushort4v o = { f2bf(v[0]*inv), f2bf(v[1]*inv), f2bf(v[2]*inv), f2bf(v[3]*inv) };
  *((ushort4v*)(wbf + (size_t)k * D_DIM) + threadIdx.x) = o;
}

// ---- GEMM: E[b,k] = exp( (feat_b . w_k) * SCALE ), bf16 output ----
// (unchanged from round 4 for clean attribution)
__device__ __forceinline__ void gload_lds16(const unsigned short* g, unsigned short* l) {
  __builtin_amdgcn_global_load_lds(
      (const __attribute__((address_space(1))) void*)g,
      (__attribute__((address_space(3))) void*)l, 16, 0, 0);
}

__global__ __launch_bounds__(256) void gemm_exp_kernel(const unsigned short* __restrict__ fbf,
                                                       const unsigned short* __restrict__ wbf,
                                                       unsigned short* __restrict__ Emat,
                                                       float* __restrict__ rowsum) {
  __shared__ unsigned short sA[128 * 32];
  __shared__ unsigned short sB[128 * 32];
  const int tid  = threadIdx.x;
  const int lane = tid & 63;
  const int wid  = tid >> 6;
  const int wr = wid >> 1, wc = wid & 1;
  const int m0 = blockIdx.x * 128;
  const int n0 = blockIdx.y * 128;

  f32x4 acc[4][4];
#pragma unroll
  for (int i = 0; i < 4; ++i)
#pragma unroll
    for (int j = 0; j < 4; ++j) acc[i][j] = (f32x4){0.f, 0.f, 0.f, 0.f};

  const int srow = (wid * 2) * 16 + (lane >> 2);
  const int scol = (lane & 3) * 8;
  const unsigned short* ga0 = fbf + (size_t)(m0 + srow) * D_DIM + scol;
  const unsigned short* gb0 = wbf + (size_t)(n0 + srow) * D_DIM + scol;
  unsigned short* la0 = &sA[(wid * 2) * 512];
  unsigned short* lb0 = &sB[(wid * 2) * 512];

  const int fr = lane & 15;
  const int fk = (lane >> 4) * 8;

  for (int kt = 0; kt < D_DIM / 32; ++kt) {
    const int kk = kt * 32;
    if (kt) __syncthreads();
    gload_lds16(ga0 + kk,              la0);
    gload_lds16(ga0 + 16 * D_DIM + kk, la0 + 512);
    gload_lds16(gb0 + kk,              lb0);
    gload_lds16(gb0 + 16 * D_DIM + kk, lb0 + 512);
    __syncthreads();

    short8 af[4], bfr[4];
#pragma unroll
    for (int mi = 0; mi < 4; ++mi)
      af[mi] = *(const short8*)&sA[(wr * 64 + mi * 16 + fr) * 32 + fk];
#pragma unroll
    for (int ni = 0; ni < 4; ++ni)
      bfr[ni] = *(const short8*)&sB[(wc * 64 + ni * 16 + fr) * 32 + fk];
#pragma unroll
    for (int mi = 0; mi < 4; ++mi)
#pragma unroll
      for (int ni = 0; ni < 4; ++ni)
        acc[mi][ni] = __builtin_amdgcn_mfma_f32_16x16x32_bf16(af[mi], bfr[ni], acc[mi][ni], 0, 0, 0);
  }

  const int fq = lane >> 4;
#pragma unroll
  for (int mi = 0; mi < 4; ++mi) {
#pragma unroll
    for (int r = 0; r < 4; ++r) {
      const int row = m0 + wr * 64 + mi * 16 + fq * 4 + r;
      const size_t base = (size_t)row * K_DIM + n0 + wc * 64 + fr;
      float ps = 0.f;
#pragma unroll
      for (int ni = 0; ni < 4; ++ni) {
        float ev = __expf(acc[mi][ni][r] * SCALE);
        Emat[base + ni * 16] = f2bf(ev);
        ps += ev;
      }
      ps += __shfl_xor(ps, 1); ps += __shfl_xor(ps, 2);
      ps += __shfl_xor(ps, 4); ps += __shfl_xor(ps, 8);
      if (fr == 0) atomicAdd(&rowsum[row], ps);
    }
  }
}

// ---- beta init: beta[b] = 1/rowsum[b] ----
__global__ __launch_bounds__(256) void beta_init_kernel(const float* __restrict__ rowsum,
                                                        float* __restrict__ beta) {
  const int b = blockIdx.x * 256 + threadIdx.x;
  beta[b] = 1.0f / rowsum[b];
}

// ---- row pass (wave-per-row): s = sum_k E[b,k]*alpha[k]; beta *= c/(beta*s+TINY) ----
// grid B/4 = 2048 blocks, 4 waves per block, no __syncthreads.
__global__ __launch_bounds__(256) void row_kernel(const unsigned short* __restrict__ Emat,
                                                  const float* __restrict__ alpha,
                                                  float* __restrict__ beta) {
  const int lane = threadIdx.x & 63;
  const int b = blockIdx.x * 4 + (threadIdx.x >> 6);
  const ushort8* pe = (const ushort8*)(Emat + (size_t)b * K_DIM);
  const floatv4* pa = (const floatv4*)alpha;
  float s = 0.f;
#pragma unroll
  for (int j = 0; j < 8; ++j) {
    ushort8 e = pe[j * 64 + lane];
    floatv4 a0 = pa[j * 128 + lane * 2];
    floatv4 a1 = pa[j * 128 + lane * 2 + 1];
#pragma unroll
    for (int q = 0; q < 4; ++q) {
      s = fmaf(bf2f(e[q]),     a0[q], s);
      s = fmaf(bf2f(e[4 + q]), a1[q], s);
    }
  }
#pragma unroll
  for (int m = 32; m > 0; m >>= 1) s += __shfl_xor(s, m);
  if (lane == 0) {
    float bb = beta[b];
    beta[b] = bb * (C_B / (bb * s + TINY_F));
  }
}

// ---- col pass (atomic-free): partial[by][k] = sum over 128-row chunk of E[b,k]*beta[b] ----
// grid (K/512=8, B/128=64); wave-group wg covers 32 rows; LDS reduce; float4 stores.
__global__ __launch_bounds__(256) void col_kernel(const unsigned short* __restrict__ Emat,
                                                  const float* __restrict__ beta,
                                                  float* __restrict__ partial) {
  const int lane = threadIdx.x & 63;
  const int wg   = threadIdx.x >> 6;
  const int k0 = blockIdx.x * 512 + lane * 8;
  const int b0 = blockIdx.y * 128 + wg * 32;
  const ushort8* p = (const ushort8*)(Emat + (size_t)b0 * K_DIM + k0);
  float acc[8] = {0.f, 0.f, 0.f, 0.f, 0.f, 0.f, 0.f, 0.f};
#pragma unroll
  for (int i = 0; i < 32; ++i) {
    ushort8 e = p[(size_t)i * (K_DIM / 8)];
    float bb = beta[b0 + i];
#pragma unroll
    for (int j = 0; j < 8; ++j) acc[j] = fmaf(bf2f(e[j]), bb, acc[j]);
  }
  __shared__ float red[3][512];
  if (wg > 0) {
#pragma unroll
    for (int j = 0; j < 8; ++j) red[wg - 1][lane * 8 + j] = acc[j];
  }
  __syncthreads();
  if (wg == 0) {
    floatv4 o0, o1;
#pragma unroll
    for (int j = 0; j < 8; ++j) {
      float v = acc[j] + red[0][lane * 8 + j] + red[1][lane * 8 + j] + red[2][lane * 8 + j];
      if (j < 4) o0[j] = v; else o1[j - 4] = v;
    }
    floatv4* po = (floatv4*)(partial + (size_t)blockIdx.y * K_DIM + k0);
    po[0] = o0; po[1] = o1;
  }
}

// ---- alpha update: t[k] = sum of 64 partials; u = alpha*t; alpha *= r/(u+TINY) ----
template <int FIRST>
__global__ __launch_bounds__(256) void alpha_kernel(const float* __restrict__ partial,
                                                    float* __restrict__ alpha) {
  const int k = blockIdx.x * 256 + threadIdx.x;
  float t = 0.f;
#pragma unroll 8
  for (int i = 0; i < B_DIM / 128; ++i) t += partial[(size_t)i * K_DIM + k];
  if (FIRST) {
    alpha[k] = R_K / (t + TINY_F);
  } else {
    float a = alpha[k];
    alpha[k] = a * R_K / (a * t + TINY_F);
  }
}

// ---- fused lse+loss (wave-per-row): contrib[b] = (M+log S) - NUM/DEN ----
__global__ __launch_bounds__(256) void loss_row_kernel(const unsigned short* __restrict__ Emat,
                                                       const float* __restrict__ logits,
                                                       const float* __restrict__ alpha,
                                                       float* __restrict__ contrib) {
  const int lane = threadIdx.x & 63;
  const int b = blockIdx.x * 4 + (threadIdx.x >> 6);
  const floatv4* pl = (const floatv4*)(logits + (size_t)b * K_DIM);
  const ushort8* pe = (const ushort8*)(Emat + (size_t)b * K_DIM);
  const floatv4* pa = (const floatv4*)alpha;

  floatv4 lg[16];
#pragma unroll
  for (int j = 0; j < 8; ++j) {
    lg[2 * j]     = pl[j * 128 + lane * 2];
    lg[2 * j + 1] = pl[j * 128 + lane * 2 + 1];
  }
  float m = lg[0][0];
#pragma unroll
  for (int q = 0; q < 16; ++q)
#pragma unroll
    for (int t = 0; t < 4; ++t) m = fmaxf(m, lg[q][t]);
#pragma unroll
  for (int mm = 32; mm > 0; mm >>= 1) m = fmaxf(m, __shfl_xor(m, mm));

  float s = 0.f, num = 0.f, den = 0.f;
#pragma unroll
  for (int j = 0; j < 8; ++j) {
    ushort8 e  = pe[j * 64 + lane];
    floatv4 a0 = pa[j * 128 + lane * 2];
    floatv4 a1 = pa[j * 128 + lane * 2 + 1];
    floatv4 l0 = lg[2 * j], l1 = lg[2 * j + 1];
#pragma unroll
    for (int q = 0; q < 4; ++q) {
      s += __expf(l0[q] - m) + __expf(l1[q] - m);
      float ea;
      ea = bf2f(e[q])     * a0[q]; den += ea; num += ea * l0[q];
      ea = bf2f(e[4 + q]) * a1[q]; den += ea; num += ea * l1[q];
    }
  }
#pragma unroll
  for (int mm = 32; mm > 0; mm >>= 1) {
    s   += __shfl_xor(s, mm);
    num += __shfl_xor(num, mm);
    den += __shfl_xor(den, mm);
  }
  if (lane == 0) contrib[b] = (m + __logf(s)) - num / den;
}

// ---- final: out = mean(contrib) ----
__global__ __launch_bounds__(256) void final_reduce_kernel(const float* __restrict__ contrib,
                                                           float* __restrict__ out) {
  float s = 0.f;
  const floatv4* p = (const floatv4*)contrib + threadIdx.x;
#pragma unroll
  for (int i = 0; i < 8; ++i) {
    floatv4 v = p[i * 256];
    s += v[0] + v[1] + v[2] + v[3];
  }
  __shared__ float sm[8];
  float tot = blk_sum(s, sm);
  if (threadIdx.x == 0) *out = tot * (1.0f / (float)B_DIM);
}

extern "C" void kernel_launch(void* const* d_in, const int* in_sizes, int n_in,
                              void* d_out, int out_size, void* d_ws, size_t ws_size,
                              hipStream_t stream) {
  (void)in_sizes; (void)n_in; (void)out_size; (void)ws_size;
  const float* feat   = (const float*)d_in[0];  // [8192,1024]
  const float* protos = (const float*)d_in[1];  // [4096,1024]
  const float* logits = (const float*)d_in[2];  // [8192,4096]
  float* out = (float*)d_out;

  char* ws = (char*)d_ws;
  // layout (bytes):
  float*          rowsum  = (float*)(ws + 0);                 // 8192 f32 (zeroed)
  float*          alpha   = (float*)(ws + 32768);             // 4096 f32
  float*          beta    = (float*)(ws + 49152);             // 8192 f32
  float*          contrib = (float*)(ws + 81920);             // 8192 f32
  unsigned short* wbf     = (unsigned short*)(ws + 114688);   // 4096*1024 bf16
  unsigned short* fbf     = (unsigned short*)(ws + 8503296);  // 8192*1024 bf16
  float*          partial = (float*)(ws + 8503296);           // 64*4096 f32, ALIASES fbf
                                                              // (fbf dead after gemm)
  unsigned short* Emat    = (unsigned short*)(ws + 25280512); // 8192*4096 bf16

  hipMemsetAsync(rowsum, 0, B_DIM * sizeof(float), stream);

  cvt_kernel<<<(B_DIM * D_DIM) / (256 * 16), 256, 0, stream>>>(feat, fbf);
  protonorm_kernel<<<K_DIM, 256, 0, stream>>>(protos, wbf);
  gemm_exp_kernel<<<dim3(B_DIM / 128, K_DIM / 128), 256, 0, stream>>>(fbf, wbf, Emat, rowsum);
  beta_init_kernel<<<B_DIM / 256, 256, 0, stream>>>(rowsum, beta);

  // Sinkhorn (alpha/beta factored; beta cancels in final normalization)
  col_kernel<<<dim3(K_DIM / 512, B_DIM / 128), 256, 0, stream>>>(Emat, beta, partial);
  alpha_kernel<1><<<K_DIM / 256, 256, 0, stream>>>(partial, alpha);          // iter1 u
  row_kernel<<<B_DIM / 4, 256, 0, stream>>>(Emat, alpha, beta);              // iter1 v
  col_kernel<<<dim3(K_DIM / 512, B_DIM / 128), 256, 0, stream>>>(Emat, beta, partial);
  alpha_kernel<0><<<K_DIM / 256, 256, 0, stream>>>(partial, alpha);          // iter2 u
  row_kernel<<<B_DIM / 4, 256, 0, stream>>>(Emat, alpha, beta);              // iter2 v
  col_kernel<<<dim3(K_DIM / 512, B_DIM / 128), 256, 0, stream>>>(Emat, beta, partial);
  alpha_kernel<0><<<K_DIM / 256, 256, 0, stream>>>(partial, alpha);          // iter3 u
  // iter3 v and final col-norm cancel in the loss -> skip

  loss_row_kernel<<<B_DIM / 4, 256, 0, stream>>>(Emat, logits, alpha, contrib);
  final_reduce_kernel<<<1, 256, 0, stream>>>(contrib, out);
}